// Round 13
// baseline (386.384 us; speedup 1.0000x reference)
//
#include <hip/hip_runtime.h>

#define TT    512
#define HH    64
#define NB    4
#define NBLK  256
#define HP    80    // h batch pitch in f16 (r21: 2-way banks, free)

#define LOG2E 1.44269504f

typedef _Float16 f16x8 __attribute__((ext_vector_type(8)));
typedef float    f32x4 __attribute__((ext_vector_type(4)));

#if __has_builtin(__builtin_amdgcn_exp2f)
#define EXP2(x) __builtin_amdgcn_exp2f(x)
#else
#define EXP2(x) exp2f(x)
#endif

// r22 = r21's swapped-operand MFMA body at 4-wave geometry (discriminating
// experiment: is the ~600cy/tick unexplained stall 8-wave barrier skew +
// 2-waves/SIMD round-robin, or intrinsic chain latency?).
// 256 blocks x 256 threads: waves 0-1 = A (layer 1), waves 2-3 = C (layer 2).
// Each wave owns 8 M-tiles: arow = 16w + 32*g8 + n, g8=0..7 -> tile g8 is
// gate (g8>>1) of units 32*(g8&1)+16w+[0..16). ONE wave per SIMD (no intra-
// SIMD pipe contention), 4-wave barrier (half the rendezvous width).
// Swapped MFMA (r21): D = A.B, A = h^T batch-replicated (A-row m = batch
// m>>2), B = W^T (B-col n = weight row arow). Lane (n,quad) holds gates of
// cells (unit 32h+16w+n, batch quad) in acc[2g+h][0]: pointwise on all 64
// lanes, 2 cells/lane (independent -> ILP), zero post-MFMA data movement.
// Same per-gate K-order as r21 -> bitwise identical (absmax 9.765e-4).
// Carries r17 rcp pointwise + r18/r19 exp2/sign folding.
// LESSONS: r8 cross-block 4x. r10 16-lane pointwise 2x. r12/r20 co-residency
// can't shorten the chain. r13 128t left 2 SIMDs idle (NOT a fat-wave
// verdict). r14 chain cuts neutral pre-r17. r16 spin-barriers worse. r17 rcp
// -19%. r18 bundling. r21 transpose-free layout -28%, conflicts ~0.
__device__ __forceinline__ float sig2_(float xs) {   // xs = -x*log2e (pre-folded)
    return __builtin_amdgcn_rcpf(1.0f + EXP2(xs));
}
__device__ __forceinline__ float tanh2_(float xs) {  // xs = 2x*log2e (pre-folded)
    return 1.0f - 2.0f * __builtin_amdgcn_rcpf(1.0f + EXP2(xs));
}

__global__ __launch_bounds__(256, 1) void lstm_mfma(
    const float* __restrict__ x,
    const float* __restrict__ w_ih0, const float* __restrict__ w_hh0,
    const float* __restrict__ b_ih0, const float* __restrict__ b_hh0,
    const float* __restrict__ w_ih1, const float* __restrict__ w_hh1,
    const float* __restrict__ b_ih1, const float* __restrict__ b_hh1,
    const float* __restrict__ w_out, const float* __restrict__ b_out,
    float* __restrict__ out)
{
    __shared__ __align__(16) _Float16 h1T[2][4 * HP];   // h1 [batch][unit] f16
    __shared__ __align__(16) _Float16 h2T[2][4 * HP];   // h2 [batch][unit] f16
    __shared__ float xs[TT * 12];                       // x [t][d][4] fp32
    __shared__ __align__(16) float h2f[4 * 68];         // final h2 fp32
    __shared__ float lg[NB][4];

    const int tid   = threadIdx.x;
    const int group = tid >> 7;          // 0 = A (layer 1), 1 = C (layer 2)
    const int w     = (tid >> 6) & 1;    // wave-in-group (0..1)
    const int lane  = tid & 63;
    const int quad  = lane >> 4;
    const int n     = lane & 15;         // B-col = weight-row-in-tile; A-row idx
    const int bq    = n >> 2;            // batch carried by this lane's A-row
    const int b0    = blockIdx.x * NB;

    // ---- persistent weight fragments: 8 tiles/wave ----
    // tile g8: weight rows arow = 16w + 32*g8 + n -> gate g8>>1, unit-half g8&1.
    // Gate-scaled (r18 folding): i,f,o x(-log2e), g x(2log2e).
    f16x8 whh[8][2], wih[8][2], axf[8];
    f32x4 biasf[8];
    #pragma unroll
    for (int g8 = 0; g8 < 8; ++g8) {
        const float sc = ((g8 >> 1) == 2) ? (2.0f * LOG2E) : (-LOG2E);
        const int arow = 16 * w + 32 * g8 + n;        // weight row of B-col n
        const float* ph = (group == 0) ? (w_hh0 + arow * HH) : (w_hh1 + arow * HH);
        const float* pi = w_ih1 + arow * HH;
        #pragma unroll
        for (int k0 = 0; k0 < 2; ++k0) {
            #pragma unroll
            for (int j = 0; j < 8; ++j) {
                whh[g8][k0][j] = (_Float16)(sc * ph[quad * 8 + 32 * k0 + j]);
                wih[g8][k0][j] = (group == 1) ? (_Float16)(sc * pi[quad * 8 + 32 * k0 + j])
                                              : (_Float16)0.f;
            }
        }
        const float bv = sc * ((group == 0) ? (b_ih0[arow] + b_hh0[arow])
                                            : (b_ih1[arow] + b_hh1[arow]));
        #pragma unroll
        for (int r = 0; r < 4; ++r) biasf[g8][r] = bv;
        f16x8 ax;
        #pragma unroll
        for (int j = 0; j < 8; ++j) ax[j] = (_Float16)0.f;
        if (group == 0 && quad == 0) {                // K=3 x-transform (scaled)
            ax[0] = (_Float16)(sc * w_ih0[arow * 3 + 0]);
            ax[1] = (_Float16)(sc * w_ih0[arow * 3 + 1]);
            ax[2] = (_Float16)(sc * w_ih0[arow * 3 + 2]);
        }
        axf[g8] = ax;
    }

    // ---- LDS init ----
    for (int i = tid; i < 2 * 4 * HP / 2; i += 256) {   // ints
        ((int*)h1T)[i] = 0;
        ((int*)h2T)[i] = 0;
    }
    for (int i = tid; i < TT * 12; i += 256) {
        const int t = i / 12, rem = i - t * 12;
        const int d = rem >> 2, b = rem & 3;
        xs[i] = x[(size_t)(b0 + b) * (TT * 3) + t * 3 + d];
    }
    __syncthreads();

    float creg[2] = {0.f, 0.f};   // cells (unit 32h+16w+n, batch quad), h=0,1

    for (int t = 0; t <= TT; ++t) {
        if (group == 0) {
            if (t < TT) {
                f16x8 bx;                              // A-operand: x, batch bq
                #pragma unroll
                for (int j = 0; j < 8; ++j) bx[j] = (_Float16)0.f;
                if (quad == 0) {
                    const float* xp = xs + t * 12 + bq;
                    bx[0] = (_Float16)xp[0];
                    bx[1] = (_Float16)xp[4];
                    bx[2] = (_Float16)xp[8];
                }
                const _Float16* hsrc = h1T[(t + 1) & 1];
                const f16x8 bh0 = *(const f16x8*)(hsrc + bq * HP + quad * 8);
                const f16x8 bh1 = *(const f16x8*)(hsrc + bq * HP + quad * 8 + 32);
                f32x4 acc[8];
                #pragma unroll
                for (int g8 = 0; g8 < 8; ++g8) {
                    f32x4 a = __builtin_amdgcn_mfma_f32_16x16x32_f16(bx, axf[g8], biasf[g8], 0, 0, 0);
                    a = __builtin_amdgcn_mfma_f32_16x16x32_f16(bh0, whh[g8][0], a, 0, 0, 0);
                    a = __builtin_amdgcn_mfma_f32_16x16x32_f16(bh1, whh[g8][1], a, 0, 0, 0);
                    acc[g8] = a;
                }
                #pragma unroll
                for (int h = 0; h < 2; ++h) {          // 2 cells/lane, independent
                    const float is = sig2_(acc[0 + h][0]);
                    const float fs = sig2_(acc[2 + h][0]);
                    const float gt = tanh2_(acc[4 + h][0]);
                    const float os = sig2_(acc[6 + h][0]);
                    creg[h] = fs * creg[h] + is * gt;
                    h1T[t & 1][quad * HP + 32 * h + 16 * w + n] =
                        (_Float16)(os * tanh2_(creg[h] * (2.0f * LOG2E)));
                }
            }
        } else {
            if (t >= 1) {
                // fused K=128 matvec over [h1(t-1); h2(t-2)], 4-deep chains
                const _Float16* h1src = h1T[(t + 1) & 1];
                const _Float16* h2src = h2T[(t + 1) & 1];
                const f16x8 b10 = *(const f16x8*)(h1src + bq * HP + quad * 8);
                const f16x8 b11 = *(const f16x8*)(h1src + bq * HP + quad * 8 + 32);
                const f16x8 b20 = *(const f16x8*)(h2src + bq * HP + quad * 8);
                const f16x8 b21 = *(const f16x8*)(h2src + bq * HP + quad * 8 + 32);
                f32x4 acc[8];
                #pragma unroll
                for (int g8 = 0; g8 < 8; ++g8) {
                    f32x4 a = __builtin_amdgcn_mfma_f32_16x16x32_f16(b10, wih[g8][0], biasf[g8], 0, 0, 0);
                    a = __builtin_amdgcn_mfma_f32_16x16x32_f16(b11, wih[g8][1], a, 0, 0, 0);
                    a = __builtin_amdgcn_mfma_f32_16x16x32_f16(b20, whh[g8][0], a, 0, 0, 0);
                    a = __builtin_amdgcn_mfma_f32_16x16x32_f16(b21, whh[g8][1], a, 0, 0, 0);
                    acc[g8] = a;
                }
                #pragma unroll
                for (int h = 0; h < 2; ++h) {
                    const float is = sig2_(acc[0 + h][0]);
                    const float fs = sig2_(acc[2 + h][0]);
                    const float gt = tanh2_(acc[4 + h][0]);
                    const float os = sig2_(acc[6 + h][0]);
                    creg[h] = fs * creg[h] + is * gt;
                    const float hh_ = os * tanh2_(creg[h] * (2.0f * LOG2E));
                    h2T[t & 1][quad * HP + 32 * h + 16 * w + n] = (_Float16)hh_;
                    if (t == TT) h2f[quad * 68 + 32 * h + 16 * w + n] = hh_;
                }
            }
        }
        __syncthreads();
    }

    // ---- epilogue: logits + softmax on fp32 h2 ----
    if (tid < 16) {
        const int b = tid & 3, o = tid >> 2;
        float acc = b_out[o];
        #pragma unroll
        for (int j = 0; j < HH; ++j)
            acc = fmaf(w_out[o * HH + j], h2f[b * 68 + j], acc);
        lg[b][o] = acc;
    }
    __syncthreads();
    if (tid < NB) {
        const int b = tid;
        const float l0 = lg[b][0], l1 = lg[b][1], l2 = lg[b][2], l3 = lg[b][3];
        const float m  = fmaxf(fmaxf(l0, l1), fmaxf(l2, l3));
        const float e0 = __expf(l0 - m), e1 = __expf(l1 - m);
        const float e2 = __expf(l2 - m), e3 = __expf(l3 - m);
        const float sum = 1.0f / (e0 + e1 + e2 + e3);
        out[(b0 + b) * 4 + 0] = e0 * sum;
        out[(b0 + b) * 4 + 1] = e1 * sum;
        out[(b0 + b) * 4 + 2] = e2 * sum;
        out[(b0 + b) * 4 + 3] = e3 * sum;
    }
}

extern "C" void kernel_launch(void* const* d_in, const int* in_sizes, int n_in,
                              void* d_out, int out_size, void* d_ws, size_t ws_size,
                              hipStream_t stream) {
    const float* x     = (const float*)d_in[0];
    const float* w_ih0 = (const float*)d_in[1];
    const float* w_hh0 = (const float*)d_in[2];
    const float* b_ih0 = (const float*)d_in[3];
    const float* b_hh0 = (const float*)d_in[4];
    const float* w_ih1 = (const float*)d_in[5];
    const float* w_hh1 = (const float*)d_in[6];
    const float* b_ih1 = (const float*)d_in[7];
    const float* b_hh1 = (const float*)d_in[8];
    const float* w_out = (const float*)d_in[9];
    const float* b_out = (const float*)d_in[10];
    float* out = (float*)d_out;

    hipLaunchKernelGGL(lstm_mfma, dim3(NBLK), dim3(256), 0, stream,
                       x, w_ih0, w_hh0, b_ih0, b_hh0,
                       w_ih1, w_hh1, b_ih1, b_hh1,
                       w_out, b_out, out);
}

// Round 14
// 315.357 us; speedup vs baseline: 1.2252x; 1.2252x over previous
//
#include <hip/hip_runtime.h>

#define TT    512
#define HH    64
#define NB    4
#define NBLK  256
#define HP    80    // h batch pitch in f16 (r21: 2-way banks, free)

#define LOG2E 1.44269504f

typedef _Float16 f16x8 __attribute__((ext_vector_type(8)));
typedef float    f32x4 __attribute__((ext_vector_type(4)));

#if __has_builtin(__builtin_amdgcn_exp2f)
#define EXP2(x) __builtin_amdgcn_exp2f(x)
#else
#define EXP2(x) exp2f(x)
#endif

// r23 = r21 (270us proven backbone) + C-chain 2+2 split, SINGLE change.
// r21 recap: swapped-operand MFMA (A = h^T batch-replicated rows, B = W^T),
// lane (n,quad) holds all 4 gates of cell (unit 16w+n, batch quad) in
// acc[g][0] -> pointwise on all 64 lanes, zero post-MFMA data movement,
// bank conflicts ~0 (cell-transpose deleted). rcp pointwise (r17) +
// exp2/sign weight folding (r18/r19).
// r23 change: C's 4-deep dependent MFMA chain split into two INDEPENDENT
// 2-chains (p = bias + Wih.h1; q = Whh.h2) combined by ONE scalar add on
// component 0 (the only component consumed). This halves the C chain's
// MFMA RAW-latency depth — the largest unmeasured chunk of the ~950cy
// per-tick stall. r18's split regression does not apply: that structure
// needed all 4 acc components (cell-transpose write) + 16 adds; here 4
// scalar adds, nothing else. Reorder = r10/r18-measured absmax ~1e-3.
// If neutral: MFMA RAW latency is small -> residual stall is LDS/barrier
// intrinsic.
// LESSONS: r8 cross-block 4x. r10 16-lane pointwise 2x. r12/r20 co-res
// can't shorten chain. r13/r15/r22 fat waves lose (r22: 1 wave/SIMD 350us
// vs 2/SIMD 270us — second wave fills stalls). r14 chain cuts neutral
// pre-r17. r16 spin-barriers worse. r17 rcp -19%. r21 swapped-operand -28%.
__device__ __forceinline__ float sig2_(float xs) {   // xs = -x*log2e (pre-folded)
    return __builtin_amdgcn_rcpf(1.0f + EXP2(xs));
}
__device__ __forceinline__ float tanh2_(float xs) {  // xs = 2x*log2e (pre-folded)
    return 1.0f - 2.0f * __builtin_amdgcn_rcpf(1.0f + EXP2(xs));
}

__global__ __launch_bounds__(512) void lstm_mfma(
    const float* __restrict__ x,
    const float* __restrict__ w_ih0, const float* __restrict__ w_hh0,
    const float* __restrict__ b_ih0, const float* __restrict__ b_hh0,
    const float* __restrict__ w_ih1, const float* __restrict__ w_hh1,
    const float* __restrict__ b_ih1, const float* __restrict__ b_hh1,
    const float* __restrict__ w_out, const float* __restrict__ b_out,
    float* __restrict__ out)
{
    __shared__ __align__(16) _Float16 h1T[2][4 * HP];   // h1 [batch][unit] f16
    __shared__ __align__(16) _Float16 h2T[2][4 * HP];   // h2 [batch][unit] f16
    __shared__ float xs[TT * 12];                       // x [t][d][4] fp32
    __shared__ __align__(16) float h2f[4 * 68];         // final h2 fp32
    __shared__ float lg[NB][4];

    const int tid   = threadIdx.x;
    const int group = tid >> 8;          // 0 = A (layer 1), 1 = C (layer 2)
    const int w     = (tid >> 6) & 3;    // wave-in-group
    const int lane  = tid & 63;
    const int quad  = lane >> 4;
    const int n     = lane & 15;         // B-col = weight-row-in-tile; A-row idx
    const int bq    = n >> 2;            // batch carried by this lane's A-row
    const int b0    = blockIdx.x * NB;

    // ---- persistent weight fragments (B = W^T; gate-scaled r18 folding) ----
    f16x8 whh[4][2], wih[4][2], axf[4];
    f32x4 biasf[4];
    #pragma unroll
    for (int g_ = 0; g_ < 4; ++g_) {
        const float sc = (g_ == 2) ? (2.0f * LOG2E) : (-LOG2E);
        const int arow = 16 * w + 64 * g_ + n;        // weight row of B-col n
        const float* ph = (group == 0) ? (w_hh0 + arow * HH) : (w_hh1 + arow * HH);
        const float* pi = w_ih1 + arow * HH;
        #pragma unroll
        for (int k0 = 0; k0 < 2; ++k0) {
            #pragma unroll
            for (int j = 0; j < 8; ++j) {
                whh[g_][k0][j] = (_Float16)(sc * ph[quad * 8 + 32 * k0 + j]);
                wih[g_][k0][j] = (group == 1) ? (_Float16)(sc * pi[quad * 8 + 32 * k0 + j])
                                              : (_Float16)0.f;
            }
        }
        const float bv = sc * ((group == 0) ? (b_ih0[arow] + b_hh0[arow])
                                            : (b_ih1[arow] + b_hh1[arow]));
        #pragma unroll
        for (int r = 0; r < 4; ++r) biasf[g_][r] = bv;
        f16x8 ax;
        #pragma unroll
        for (int j = 0; j < 8; ++j) ax[j] = (_Float16)0.f;
        if (group == 0 && quad == 0) {                // K=3 x-transform (scaled)
            ax[0] = (_Float16)(sc * w_ih0[arow * 3 + 0]);
            ax[1] = (_Float16)(sc * w_ih0[arow * 3 + 1]);
            ax[2] = (_Float16)(sc * w_ih0[arow * 3 + 2]);
        }
        axf[g_] = ax;
    }

    // ---- LDS init ----
    for (int i = tid; i < 2 * 4 * HP / 2; i += 512) {   // ints
        ((int*)h1T)[i] = 0;
        ((int*)h2T)[i] = 0;
    }
    for (int i = tid; i < TT * 12; i += 512) {
        const int t = i / 12, rem = i - t * 12;
        const int d = rem >> 2, b = rem & 3;
        xs[i] = x[(size_t)(b0 + b) * (TT * 3) + t * 3 + d];
    }
    __syncthreads();

    float creg = 0.f;    // cell c of (unit 16w+n, batch quad)

    for (int t = 0; t <= TT; ++t) {
        if (group == 0) {
            if (t < TT) {
                f16x8 bx;                              // A-operand: x, batch bq
                #pragma unroll
                for (int j = 0; j < 8; ++j) bx[j] = (_Float16)0.f;
                if (quad == 0) {
                    const float* xp = xs + t * 12 + bq;
                    bx[0] = (_Float16)xp[0];
                    bx[1] = (_Float16)xp[4];
                    bx[2] = (_Float16)xp[8];
                }
                const _Float16* hsrc = h1T[(t + 1) & 1];
                const f16x8 bh0 = *(const f16x8*)(hsrc + bq * HP + quad * 8);
                const f16x8 bh1 = *(const f16x8*)(hsrc + bq * HP + quad * 8 + 32);
                f32x4 acc[4];
                #pragma unroll
                for (int g_ = 0; g_ < 4; ++g_) {
                    f32x4 a = __builtin_amdgcn_mfma_f32_16x16x32_f16(bx, axf[g_], biasf[g_], 0, 0, 0);
                    a = __builtin_amdgcn_mfma_f32_16x16x32_f16(bh0, whh[g_][0], a, 0, 0, 0);
                    a = __builtin_amdgcn_mfma_f32_16x16x32_f16(bh1, whh[g_][1], a, 0, 0, 0);
                    acc[g_] = a;
                }
                const float is = sig2_(acc[0][0]);
                const float fs = sig2_(acc[1][0]);
                const float gt = tanh2_(acc[2][0]);
                const float os = sig2_(acc[3][0]);
                creg = fs * creg + is * gt;
                h1T[t & 1][quad * HP + 16 * w + n] =
                    (_Float16)(os * tanh2_(creg * (2.0f * LOG2E)));
            }
        } else {
            if (t >= 1) {
                // fused K=128 matvec over [h1(t-1); h2(t-2)]:
                // two independent 2-chains, combined on component 0 only
                const _Float16* h1src = h1T[(t + 1) & 1];
                const _Float16* h2src = h2T[(t + 1) & 1];
                const f16x8 b10 = *(const f16x8*)(h1src + bq * HP + quad * 8);
                const f16x8 b11 = *(const f16x8*)(h1src + bq * HP + quad * 8 + 32);
                const f16x8 b20 = *(const f16x8*)(h2src + bq * HP + quad * 8);
                const f16x8 b21 = *(const f16x8*)(h2src + bq * HP + quad * 8 + 32);
                const f32x4 zero4 = {0.f, 0.f, 0.f, 0.f};
                float gv[4];
                #pragma unroll
                for (int g_ = 0; g_ < 4; ++g_) {
                    f32x4 p = __builtin_amdgcn_mfma_f32_16x16x32_f16(b10, wih[g_][0], biasf[g_], 0, 0, 0);
                    p = __builtin_amdgcn_mfma_f32_16x16x32_f16(b11, wih[g_][1], p, 0, 0, 0);
                    f32x4 q4 = __builtin_amdgcn_mfma_f32_16x16x32_f16(b20, whh[g_][0], zero4, 0, 0, 0);
                    q4 = __builtin_amdgcn_mfma_f32_16x16x32_f16(b21, whh[g_][1], q4, 0, 0, 0);
                    gv[g_] = p[0] + q4[0];
                }
                const float is = sig2_(gv[0]);
                const float fs = sig2_(gv[1]);
                const float gt = tanh2_(gv[2]);
                const float os = sig2_(gv[3]);
                creg = fs * creg + is * gt;
                const float h = os * tanh2_(creg * (2.0f * LOG2E));
                h2T[t & 1][quad * HP + 16 * w + n] = (_Float16)h;   // h2(t-1)
                if (t == TT) h2f[quad * 68 + 16 * w + n] = h;       // h2(TT-1) fp32
            }
        }
        __syncthreads();
    }

    // ---- epilogue: logits + softmax on fp32 h2 ----
    if (tid < 16) {
        const int b = tid & 3, o = tid >> 2;
        float acc = b_out[o];
        #pragma unroll
        for (int j = 0; j < HH; ++j)
            acc = fmaf(w_out[o * HH + j], h2f[b * 68 + j], acc);
        lg[b][o] = acc;
    }
    __syncthreads();
    if (tid < NB) {
        const int b = tid;
        const float l0 = lg[b][0], l1 = lg[b][1], l2 = lg[b][2], l3 = lg[b][3];
        const float m  = fmaxf(fmaxf(l0, l1), fmaxf(l2, l3));
        const float e0 = __expf(l0 - m), e1 = __expf(l1 - m);
        const float e2 = __expf(l2 - m), e3 = __expf(l3 - m);
        const float sum = 1.0f / (e0 + e1 + e2 + e3);
        out[(b0 + b) * 4 + 0] = e0 * sum;
        out[(b0 + b) * 4 + 1] = e1 * sum;
        out[(b0 + b) * 4 + 2] = e2 * sum;
        out[(b0 + b) * 4 + 3] = e3 * sum;
    }
}

extern "C" void kernel_launch(void* const* d_in, const int* in_sizes, int n_in,
                              void* d_out, int out_size, void* d_ws, size_t ws_size,
                              hipStream_t stream) {
    const float* x     = (const float*)d_in[0];
    const float* w_ih0 = (const float*)d_in[1];
    const float* w_hh0 = (const float*)d_in[2];
    const float* b_ih0 = (const float*)d_in[3];
    const float* b_hh0 = (const float*)d_in[4];
    const float* w_ih1 = (const float*)d_in[5];
    const float* w_hh1 = (const float*)d_in[6];
    const float* b_ih1 = (const float*)d_in[7];
    const float* b_hh1 = (const float*)d_in[8];
    const float* w_out = (const float*)d_in[9];
    const float* b_out = (const float*)d_in[10];
    float* out = (float*)d_out;

    hipLaunchKernelGGL(lstm_mfma, dim3(NBLK), dim3(512), 0, stream,
                       x, w_ih0, w_hh0, b_ih0, b_hh0,
                       w_ih1, w_hh1, b_ih1, b_hh1,
                       w_out, b_out, out);
}